// Round 5
// baseline (168.420 us; speedup 1.0000x reference)
//
#include <hip/hip_runtime.h>
#include <math.h>

#define BATCH   4
#define S_LEN   2048
#define DMODEL  512
#define NHEADS  8
#define DHEAD   64
#define M_TOT   8192
#define ATT_SCALE 0.04419417382415922f   // 1/sqrt(512)
#define QSCALE (ATT_SCALE * 1.44269504088896f)  // fold log2(e): exp2 in softmax

using short8  = __attribute__((ext_vector_type(8))) short;
using short4v = __attribute__((ext_vector_type(4))) short;
using floatx4 = __attribute__((ext_vector_type(4))) float;

// fp32 -> bf16 RNE
__device__ __forceinline__ ushort f2bf(float f) {
    union { float f; unsigned u; } x; x.f = f;
    unsigned u = x.u + 0x7FFFu + ((x.u >> 16) & 1u);
    return (ushort)(u >> 16);
}
__device__ __forceinline__ unsigned pk2(float a, float b) {
    return (unsigned)f2bf(a) | ((unsigned)f2bf(b) << 16);
}
// fp32x2 -> packed bf16x2, round-half-up — hot-loop use
__device__ __forceinline__ unsigned pkr2(float a, float b) {
    unsigned ua = __float_as_uint(a) + 0x8000u;
    unsigned ub = __float_as_uint(b) + 0x8000u;
    return __builtin_amdgcn_perm(ub, ua, 0x07060302u);
}

// async global->LDS, 16B per lane.  dst must be the WAVE-UNIFORM base;
// HW writes base + lane*16 (linear).  src is per-lane.
__device__ __forceinline__ void gld16(const ushort* g, ushort* l) {
    typedef const __attribute__((address_space(1))) unsigned gq_t;
    typedef __attribute__((address_space(3))) unsigned lw_t;
    __builtin_amdgcn_global_load_lds((gq_t*)g, (lw_t*)l, 16, 0, 0);
}

// ---------------------------------------------------------------------------
// Preprocess: blocks [0,4096) x fp32->bf16; [4096,4352) W transpose to bf16.
// ---------------------------------------------------------------------------
__global__ __launch_bounds__(256) void prep(
    const float* __restrict__ x,
    const float* __restrict__ Wq, const float* __restrict__ Wk,
    const float* __restrict__ Wv, const float* __restrict__ Wo,
    ushort* __restrict__ xb, ushort* __restrict__ WT)
{
    const int bid = blockIdx.x;
    if (bid < 4096) {
        const int i = (bid * 256 + threadIdx.x) * 4;
        float4 f = *(const float4*)(x + i);
        uint2 o; o.x = pk2(f.x, f.y); o.y = pk2(f.z, f.w);
        *(uint2*)(xb + i) = o;
    } else {
        const int rb = bid - 4096;
        const int p  = rb >> 6;
        const int rem = rb & 63;
        const int n  = (rem >> 5) * 256 + threadIdx.x;
        const int k0 = (rem & 31) * 16;
        const float* W = (p == 0) ? Wq : (p == 1) ? Wk : (p == 2) ? Wv : Wo;
        unsigned u[8];
        #pragma unroll
        for (int j = 0; j < 8; ++j) {
            float a = W[(k0 + 2 * j)     * DMODEL + n];
            float b = W[(k0 + 2 * j + 1) * DMODEL + n];
            u[j] = pk2(a, b);
        }
        ushort* dst = WT + ((size_t)p * DMODEL + n) * DMODEL + k0;
        *(uint4*)dst       = *(uint4*)&u[0];
        *(uint4*)(dst + 8) = *(uint4*)&u[4];
    }
}

// ---------------------------------------------------------------------------
// Kernel 1: fused QKV projection, 128x128 tile, BK=32.  Staging now via
// global_load_lds width=16 into LINEAR [128][32] tiles (m97 structure —
// the catalog's +67% lever vs VGPR round-trip staging).  Q pre-scaled by
// QSCALE; V exits via LDS transpose -> coalesced [B,H,Dh,S] b128 stores.
// ---------------------------------------------------------------------------
__global__ __launch_bounds__(256, 4) void qkv_gemm(
    const ushort* __restrict__ xb, const ushort* __restrict__ WT,
    const float* __restrict__ bq, const float* __restrict__ bk, const float* __restrict__ bv,
    ushort* __restrict__ q, ushort* __restrict__ k, ushort* __restrict__ vT)
{
    __shared__ ushort SMEM[128 * 136];   // A+B linear (16 KB) in K-loop; CT overlay (34.8 KB)
    ushort* Abuf = SMEM;                 // [128][32] linear
    ushort* Bbuf = SMEM + 128 * 32;      // [128][32] linear
    ushort (*CT)[136] = (ushort(*)[136])SMEM;

    const int tid = threadIdx.x;
    const int wv  = tid >> 6, lane = tid & 63, l16 = lane & 15, quad = lane >> 4;
    const int m0  = blockIdx.x * 128;
    const int ng0 = blockIdx.y * 128;
    const int p   = ng0 >> 9;
    const int n0  = ng0 & 511;
    const ushort* Wp  = WT + (size_t)p * DMODEL * DMODEL + (size_t)n0 * DMODEL;
    const float* bias = (p == 0) ? bq : (p == 1) ? bk : bv;
    const float scl   = (p == 0) ? QSCALE : 1.0f;

    const int wm = (wv & 1) * 64, wn = (wv >> 1) * 64;
    floatx4 acc[4][4] = {};

    // gload_lds lane map: lane l -> row (l>>2), col (l&3)*8 within a 16-row slab
    const int srow = lane >> 2, scol = (lane & 3) * 8;

    for (int k0 = 0; k0 < DMODEL; k0 += 32) {
        #pragma unroll
        for (int j = 0; j < 2; ++j) {
            const int row = j * 64 + wv * 16;            // wave-uniform slab base
            gld16(xb + (size_t)(m0 + row + srow) * DMODEL + k0 + scol,
                  Abuf + (size_t)row * 32);
            gld16(Wp + (size_t)(row + srow) * DMODEL + k0 + scol,
                  Bbuf + (size_t)row * 32);
        }
        __syncthreads();   // compiler drains vmcnt(0) before s_barrier

        short8 af[4], bf[4];
        #pragma unroll
        for (int i = 0; i < 4; ++i) af[i] = *(const short8*)&Abuf[(wm + i * 16 + l16) * 32 + quad * 8];
        #pragma unroll
        for (int c = 0; c < 4; ++c) bf[c] = *(const short8*)&Bbuf[(wn + c * 16 + l16) * 32 + quad * 8];
        #pragma unroll
        for (int i = 0; i < 4; ++i)
            #pragma unroll
            for (int c = 0; c < 4; ++c)
                acc[i][c] = __builtin_amdgcn_mfma_f32_16x16x32_bf16(af[i], bf[c], acc[i][c], 0, 0, 0);
        __syncthreads();
    }

    if (p < 2) {
        #pragma unroll
        for (int c = 0; c < 4; ++c) {
            const int n = n0 + wn + c * 16 + l16;
            const float bb = bias[n];
            const int h = n >> 6, dh = n & 63;
            #pragma unroll
            for (int i = 0; i < 4; ++i)
                #pragma unroll
                for (int r = 0; r < 4; ++r) {
                    const int m = m0 + wm + i * 16 + quad * 4 + r;
                    const int b = m >> 11, s = m & 2047;
                    const ushort val = f2bf((acc[i][c][r] + bb) * scl);
                    if (p == 0) q[((size_t)(b * NHEADS + h) * S_LEN + s) * DHEAD + dh] = val;
                    else        k[((size_t)(b * NHEADS + h) * S_LEN + s) * DHEAD + dh] = val;
                }
        }
    } else {
        #pragma unroll
        for (int c = 0; c < 4; ++c) {
            const int n = wn + c * 16 + l16;
            const float bb = bias[n0 + n];
            #pragma unroll
            for (int i = 0; i < 4; ++i) {
                uint2 o;
                o.x = pk2(acc[i][c][0] + bb, acc[i][c][1] + bb);
                o.y = pk2(acc[i][c][2] + bb, acc[i][c][3] + bb);
                *(uint2*)&CT[n][wm + i * 16 + quad * 4] = o;
            }
        }
        __syncthreads();
        const int n  = tid >> 1, mh = (tid & 1) * 64;
        const int gn = n0 + n;
        const int h  = gn >> 6, dh = gn & 63;
        const int b  = m0 >> 11, sb = (m0 & 2047) + mh;
        ushort* dst = vT + ((size_t)(b * NHEADS + h) * DHEAD + dh) * S_LEN + sb;
        #pragma unroll
        for (int j = 0; j < 8; ++j)
            *(uint4*)(dst + j * 8) = *(const uint4*)&CT[n][mh + j * 8];
    }
}

// ---------------------------------------------------------------------------
// Kernel 2: flash attention — round-2 version (57.0 µs measured), reverted
// verbatim after the r4 restructure regressed (−83% bank conflicts, slower:
// LDS was not critical path; kernel is latency-bound).  256 thr, 128 q/block,
// S^T = K·Q^T, PV direct-from-registers, K/V dbuf, ONE barrier/iter.
// Epilogue folds 1/Σexp; writes bf16 [B,S,H*Dh].
// ---------------------------------------------------------------------------
__global__ __launch_bounds__(256, 4) void attn(
    const ushort* __restrict__ Q, const ushort* __restrict__ K,
    const ushort* __restrict__ vT,
    ushort* __restrict__ att, const int KT)
{
    __shared__ ushort Klds[2][64][72];
    __shared__ ushort Vt[2][64][72];

    const int tid = threadIdx.x;
    const int wv  = tid >> 6, lane = tid & 63, l16 = lane & 15, quad = lane >> 4;
    const int q0  = blockIdx.x * 128;
    const int bh  = blockIdx.y;
    const ushort* Qh = Q  + (size_t)bh * S_LEN * DHEAD;
    const ushort* Kh = K  + (size_t)bh * S_LEN * DHEAD;
    const ushort* Vh = vT + (size_t)bh * DHEAD * S_LEN;

    short8 qf[2][2];
    #pragma unroll
    for (int ni = 0; ni < 2; ++ni) {
        const ushort* qrow = Qh + (size_t)(q0 + wv * 32 + ni * 16 + l16) * DHEAD;
        qf[0][ni] = *(const short8*)(qrow + quad * 8);
        qf[1][ni] = *(const short8*)(qrow + 32 + quad * 8);
    }

    floatx4 oacc[4][2] = {};   // O^T: [dh-tile][q-tile]
    float lsum[2] = {0.f, 0.f};

    const int srow = tid >> 2, sc0 = (tid & 3) * 16;
    uint4 ka, kb, va, vb;
    {
        const ushort* Ks = Kh + (size_t)srow * DHEAD + sc0;
        const ushort* Vs = Vh + (size_t)srow * S_LEN + sc0;
        ka = *(const uint4*)Ks; kb = *(const uint4*)(Ks + 8);
        va = *(const uint4*)Vs; vb = *(const uint4*)(Vs + 8);
    }

    for (int kt = 0; kt < KT; ++kt) {
        const int buf = kt & 1;
        *(uint4*)&Klds[buf][srow][sc0] = ka; *(uint4*)&Klds[buf][srow][sc0 + 8] = kb;
        *(uint4*)&Vt[buf][srow][sc0]   = va; *(uint4*)&Vt[buf][srow][sc0 + 8]   = vb;
        __syncthreads();   // sole barrier: dbuf makes the tail barrier unnecessary

        if (kt + 1 < KT) {
            const ushort* Ks = Kh + (size_t)((kt + 1) * 64 + srow) * DHEAD + sc0;
            const ushort* Vs = Vh + (size_t)srow * S_LEN + (kt + 1) * 64 + sc0;
            ka = *(const uint4*)Ks; kb = *(const uint4*)(Ks + 8);
            va = *(const uint4*)Vs; vb = *(const uint4*)(Vs + 8);
        }

        #pragma unroll
        for (int mi = 0; mi < 4; ++mi) {
            // S^T for this 16-key block: lane = (key quad*4+r, q l16)
            floatx4 s0 = {}, s1 = {};
            #pragma unroll
            for (int s = 0; s < 2; ++s) {
                short8 kf = *(const short8*)&Klds[buf][mi * 16 + l16][s * 32 + quad * 8];
                s0 = __builtin_amdgcn_mfma_f32_16x16x32_bf16(kf, qf[s][0], s0, 0, 0, 0);
                s1 = __builtin_amdgcn_mfma_f32_16x16x32_bf16(kf, qf[s][1], s1, 0, 0, 0);
            }
            // V^T A-fragments for the K=16 PV MFMA: A[m=dh=c*16+l16][k=quad*4+j]
            short4v vfr[4];
            #pragma unroll
            for (int c = 0; c < 4; ++c)
                vfr[c] = *(const short4v*)&Vt[buf][c * 16 + l16][mi * 16 + quad * 4];

            // ni = 0
            {
                const float p0 = __builtin_amdgcn_exp2f(s0[0]);
                const float p1 = __builtin_amdgcn_exp2f(s0[1]);
                const float p2 = __builtin_amdgcn_exp2f(s0[2]);
                const float p3 = __builtin_amdgcn_exp2f(s0[3]);
                lsum[0] += (p0 + p1) + (p2 + p3);
                uint2 o; o.x = pkr2(p0, p1); o.y = pkr2(p2, p3);
                short4v pf; *(uint2*)&pf = o;   // keys quad*4+{0..3}, q=l16
                #pragma unroll
                for (int c = 0; c < 4; ++c)
                    oacc[c][0] = __builtin_amdgcn_mfma_f32_16x16x16bf16_1k(vfr[c], pf, oacc[c][0], 0, 0, 0);
            }
            // ni = 1
            {
                const float p0 = __builtin_amdgcn_exp2f(s1[0]);
                const float p1 = __builtin_amdgcn_exp2f(s1[1]);
                const float p2 = __builtin_amdgcn_exp2f(s1[2]);
                const float p3 = __builtin_amdgcn_exp2f(s1[3]);
                lsum[1] += (p0 + p1) + (p2 + p3);
                uint2 o; o.x = pkr2(p0, p1); o.y = pkr2(p2, p3);
                short4v pf; *(uint2*)&pf = o;
                #pragma unroll
                for (int c = 0; c < 4; ++c)
                    oacc[c][1] = __builtin_amdgcn_mfma_f32_16x16x16bf16_1k(vfr[c], pf, oacc[c][1], 0, 0, 0);
            }
        }
    }

    // full-row softmax denominators (quad-reduce over key groups)
    float rin[2];
    #pragma unroll
    for (int ni = 0; ni < 2; ++ni) {
        float t = lsum[ni];
        t += __shfl_xor(t, 16, 64);
        t += __shfl_xor(t, 32, 64);
        rin[ni] = 1.0f / t;
    }

    // normalized bf16 output, [B,S,H*Dh] row-major (= A matrix of out_gemm)
    const int b = bh >> 3, h = bh & 7;
    #pragma unroll
    for (int ni = 0; ni < 2; ++ni) {
        const int qg = q0 + wv * 32 + ni * 16 + l16;
        ushort* orow = att + ((size_t)(b * S_LEN + qg)) * DMODEL + h * DHEAD + quad * 4;
        #pragma unroll
        for (int c = 0; c < 4; ++c) {
            uint2 o;
            o.x = pk2(oacc[c][ni][0] * rin[ni], oacc[c][ni][1] * rin[ni]);
            o.y = pk2(oacc[c][ni][2] * rin[ni], oacc[c][ni][3] * rin[ni]);
            *(uint2*)(orow + c * 16) = o;
        }
    }
}

// ---------------------------------------------------------------------------
// Kernel 3: output projection — bf16 GEMM, global_load_lds staging into
// linear [64][32] + [128][32] tiles.  Tile 64(M)x128(N) -> 512 blocks.
// ---------------------------------------------------------------------------
__global__ __launch_bounds__(256, 4) void out_gemm(
    const ushort* __restrict__ att,
    const ushort* __restrict__ WoT, const float* __restrict__ bo,
    float* __restrict__ out)
{
    __shared__ ushort Abuf[64 * 32];    // linear
    __shared__ ushort Bbuf[128 * 32];   // linear

    const int tid = threadIdx.x;
    const int wv  = tid >> 6, lane = tid & 63, l16 = lane & 15, quad = lane >> 4;
    const int m0 = blockIdx.x * 64;
    const int n0 = blockIdx.y * 128;

    const int srow = lane >> 2, scol = (lane & 3) * 8;

    floatx4 acc[8] = {};

    for (int k0 = 0; k0 < DMODEL; k0 += 32) {
        gld16(att + (size_t)(m0 + wv * 16 + srow) * DMODEL + k0 + scol,
              Abuf + (size_t)(wv * 16) * 32);
        #pragma unroll
        for (int j = 0; j < 2; ++j) {
            const int row = j * 64 + wv * 16;
            gld16(WoT + (size_t)(n0 + row + srow) * DMODEL + k0 + scol,
                  Bbuf + (size_t)row * 32);
        }
        __syncthreads();

        short8 af = *(const short8*)&Abuf[(wv * 16 + l16) * 32 + quad * 8];
        #pragma unroll
        for (int c = 0; c < 8; ++c) {
            short8 bf = *(const short8*)&Bbuf[(c * 16 + l16) * 32 + quad * 8];
            acc[c] = __builtin_amdgcn_mfma_f32_16x16x32_bf16(af, bf, acc[c], 0, 0, 0);
        }
        __syncthreads();
    }

    #pragma unroll
    for (int c = 0; c < 8; ++c) {
        const int n = n0 + c * 16 + l16;
        const float bb = bo[n];
        #pragma unroll
        for (int r = 0; r < 4; ++r) {
            const int m = m0 + wv * 16 + quad * 4 + r;
            out[(size_t)m * DMODEL + n] = acc[c][r] + bb;
        }
    }
}

// ---------------------------------------------------------------------------
extern "C" void kernel_launch(void* const* d_in, const int* in_sizes, int n_in,
                              void* d_out, int out_size, void* d_ws, size_t ws_size,
                              hipStream_t stream)
{
    const float* x  = (const float*)d_in[0];
    const float* Wq = (const float*)d_in[1];
    const float* bq = (const float*)d_in[2];
    const float* Wk = (const float*)d_in[3];
    const float* bk = (const float*)d_in[4];
    const float* Wv = (const float*)d_in[5];
    const float* bv = (const float*)d_in[6];
    const float* Wo = (const float*)d_in[7];
    const float* bo = (const float*)d_in[8];
    float* out = (float*)d_out;

    ushort* ws = (ushort*)d_ws;
    const size_t SZ = (size_t)M_TOT * DMODEL;
    ushort* xb  = ws;
    ushort* WT  = ws + SZ;
    ushort* q   = WT + 4 * (size_t)DMODEL * DMODEL;
    ushort* k   = q + SZ;
    ushort* vT  = k + SZ;
    ushort* att = vT + SZ;      // [B,S,H*Dh] bf16, normalized attention output

    prep<<<4096 + 256, 256, 0, stream>>>(x, Wq, Wk, Wv, Wo, xb, WT);

    qkv_gemm<<<dim3(M_TOT / 128, 3 * DMODEL / 128), 256, 0, stream>>>(
        xb, WT, bq, bk, bv, q, k, vT);

    attn<<<dim3(S_LEN / 128, BATCH * NHEADS), 256, 0, stream>>>(
        q, k, vT, att, S_LEN / 64);

    out_gemm<<<dim3(M_TOT / 64, DMODEL / 128), 256, 0, stream>>>(
        att, WT + 3 * (size_t)DMODEL * DMODEL, bo, out);
}